// Round 1
// baseline (858.540 us; speedup 1.0000x reference)
//
#include <hip/hip_runtime.h>

typedef unsigned short u16;
typedef __attribute__((ext_vector_type(8))) short short8;
typedef __attribute__((ext_vector_type(4))) float f32x4;

__device__ __forceinline__ u16 f2bf(float f){
  unsigned u = __builtin_bit_cast(unsigned, f);
  u += 0x7fffu + ((u >> 16) & 1u);
  return (u16)(u >> 16);
}

#define GLD16(gp, lp) __builtin_amdgcn_global_load_lds(                         \
    (const __attribute__((address_space(1))) void*)(gp),                        \
    (__attribute__((address_space(3))) void*)(lp), 16, 0, 0)

// ---------------- cast fp32 -> bf16, 8 elems/thread ----------------
__global__ __launch_bounds__(256) void cast_bf16(const float* __restrict__ in,
                                                 u16* __restrict__ out, int n8){
  int i = blockIdx.x * blockDim.x + threadIdx.x;
  if (i >= n8) return;
  const f32x4* p = (const f32x4*)in + (size_t)i * 2;
  f32x4 a = p[0], b = p[1];
  short8 o;
  o[0]=f2bf(a[0]); o[1]=f2bf(a[1]); o[2]=f2bf(a[2]); o[3]=f2bf(a[3]);
  o[4]=f2bf(b[0]); o[5]=f2bf(b[1]); o[6]=f2bf(b[2]); o[7]=f2bf(b[3]);
  *(short8*)(out + (size_t)i * 8) = o;
}

// ---------------- GEMM  C[M,N] = A[M,K] @ B[N,K]^T + bias ----------------
__device__ __forceinline__ void store_val(float* p, float v){ *p = v; }
__device__ __forceinline__ void store_val(u16* p, float v){ *p = f2bf(v); }

template<typename OutT, bool RELU>
__global__ __launch_bounds__(256) void gemm_bt(
    const u16* __restrict__ A, const u16* __restrict__ B,
    const float* __restrict__ bias, OutT* __restrict__ C,
    int M, int N, int K)
{
  __shared__ __align__(16) u16 a_lds[2][128*32];
  __shared__ __align__(16) u16 b_lds[2][128*32];
  const int t = threadIdx.x, w = t >> 6, l = t & 63;
  const int m0 = blockIdx.y * 128, n0 = blockIdx.x * 128;
  const int wr = (w >> 1) * 64, wc = (w & 1) * 64;

  auto stage = [&](int buf, int kt){
    const int k0 = kt * 32;
    #pragma unroll
    for (int i = 0; i < 2; ++i){
      int s = w * 2 + i;
      const u16* ga = A + (size_t)(m0 + s*16 + (l>>2)) * K + k0 + (l&3)*8;
      GLD16(ga, &a_lds[buf][s*512]);
      const u16* gb = B + (size_t)(n0 + s*16 + (l>>2)) * K + k0 + (l&3)*8;
      GLD16(gb, &b_lds[buf][s*512]);
    }
  };

  f32x4 acc[4][4];
  #pragma unroll
  for (int m=0;m<4;++m)
    #pragma unroll
    for (int n=0;n<4;++n) acc[m][n] = (f32x4){0.f,0.f,0.f,0.f};

  stage(0, 0);
  __syncthreads();
  const int nk = K / 32;
  int cur = 0;
  for (int kt = 0; kt < nk; ++kt){
    if (kt + 1 < nk) stage(cur ^ 1, kt + 1);
    short8 af[4], bfr[4];
    #pragma unroll
    for (int m=0;m<4;++m)
      af[m] = *(const short8*)&a_lds[cur][(wr + m*16 + (l&15))*32 + (l>>4)*8];
    #pragma unroll
    for (int n=0;n<4;++n)
      bfr[n] = *(const short8*)&b_lds[cur][(wc + n*16 + (l&15))*32 + (l>>4)*8];
    #pragma unroll
    for (int m=0;m<4;++m)
      #pragma unroll
      for (int n=0;n<4;++n)
        acc[m][n] = __builtin_amdgcn_mfma_f32_16x16x32_bf16(af[m], bfr[n], acc[m][n], 0, 0, 0);
    __syncthreads();
    cur ^= 1;
  }

  #pragma unroll
  for (int n=0;n<4;++n){
    int c = n0 + wc + n*16 + (l & 15);
    float bv = bias ? bias[c] : 0.f;
    #pragma unroll
    for (int m=0;m<4;++m){
      int rbase = m0 + wr + m*16 + (l >> 4) * 4;
      #pragma unroll
      for (int j=0;j<4;++j){
        float v = acc[m][n][j] + bv;
        if (RELU) v = fmaxf(v, 0.f);
        store_val(&C[(size_t)(rbase + j) * N + c], v);
      }
    }
  }
}

// ---------------- attention: QK^T, raw scaled scores + online stats ----------------
// grid: (S/64, B*H); block 256 (4 waves, each 16 rows)
__global__ __launch_bounds__(256) void attn_qk(
    const u16* __restrict__ qkv, float* __restrict__ attn,
    float* __restrict__ mstat, float* __restrict__ lstat)
{
  __shared__ __align__(16) u16 qs[64*64];
  __shared__ __align__(16) u16 ks[2][64*64];
  const int t = threadIdx.x, w = t >> 6, l = t & 63;
  const int bh = blockIdx.y, b = bh >> 4, h = bh & 15;
  const int q0 = blockIdx.x * 64;
  const size_t qbase = (size_t)b * 1024 * 3072;

  #pragma unroll
  for (int i=0;i<2;++i){
    int s = w*2 + i;
    const u16* g = qkv + qbase + (size_t)(q0 + s*8 + (l>>3)) * 3072 + h*64 + (l&7)*8;
    GLD16(g, &qs[s*512]);
  }
  auto stageK = [&](int buf, int ct){
    #pragma unroll
    for (int i=0;i<2;++i){
      int s = w*2 + i;
      const u16* g = qkv + qbase + (size_t)(ct*64 + s*8 + (l>>3)) * 3072 + 1024 + h*64 + (l&7)*8;
      GLD16(g, &ks[buf][s*512]);
    }
  };
  stageK(0, 0);
  __syncthreads();

  float m_run[4] = {-1e30f,-1e30f,-1e30f,-1e30f};
  float l_run[4] = {0.f,0.f,0.f,0.f};
  float* attn_b = attn + (size_t)bh * 1024 * 1024;
  int cur = 0;
  for (int ct = 0; ct < 16; ++ct){
    if (ct < 15) stageK(cur ^ 1, ct + 1);
    short8 a0 = *(const short8*)&qs[(w*16 + (l&15))*64 + (l>>4)*8];
    short8 a1 = *(const short8*)&qs[(w*16 + (l&15))*64 + 32 + (l>>4)*8];
    f32x4 acc[4];
    #pragma unroll
    for (int n=0;n<4;++n) acc[n] = (f32x4){0.f,0.f,0.f,0.f};
    #pragma unroll
    for (int n=0;n<4;++n){
      short8 b0 = *(const short8*)&ks[cur][(n*16 + (l&15))*64 + (l>>4)*8];
      acc[n] = __builtin_amdgcn_mfma_f32_16x16x32_bf16(a0, b0, acc[n], 0, 0, 0);
    }
    #pragma unroll
    for (int n=0;n<4;++n){
      short8 b1 = *(const short8*)&ks[cur][(n*16 + (l&15))*64 + 32 + (l>>4)*8];
      acc[n] = __builtin_amdgcn_mfma_f32_16x16x32_bf16(a1, b1, acc[n], 0, 0, 0);
    }
    #pragma unroll
    for (int j=0;j<4;++j){
      float s0 = acc[0][j]*0.125f, s1 = acc[1][j]*0.125f;
      float s2 = acc[2][j]*0.125f, s3 = acc[3][j]*0.125f;
      float mx = fmaxf(fmaxf(s0,s1), fmaxf(s2,s3));
      #pragma unroll
      for (int o=1;o<16;o<<=1) mx = fmaxf(mx, __shfl_xor(mx, o));
      float mn = fmaxf(m_run[j], mx);
      float es = expf(s0-mn) + expf(s1-mn) + expf(s2-mn) + expf(s3-mn);
      #pragma unroll
      for (int o=1;o<16;o<<=1) es += __shfl_xor(es, o);
      l_run[j] = l_run[j] * expf(m_run[j] - mn) + es;
      m_run[j] = mn;
      float* ap = attn_b + (size_t)(q0 + w*16 + (l>>4)*4 + j) * 1024 + ct*64 + (l&15);
      ap[0] = s0; ap[16] = s1; ap[32] = s2; ap[48] = s3;
    }
    __syncthreads();
    cur ^= 1;
  }
  if ((l & 15) == 0){
    #pragma unroll
    for (int j=0;j<4;++j){
      int row = q0 + w*16 + (l>>4)*4 + j;
      mstat[bh*1024 + row] = m_run[j];
      lstat[bh*1024 + row] = l_run[j];
    }
  }
}

// ---------------- attention: finalize softmax in-place + P@V ----------------
// grid: (S/64, B*H); block 256
__global__ __launch_bounds__(256) void attn_pv(
    const u16* __restrict__ qkv, float* __restrict__ attn,
    const float* __restrict__ mstat, const float* __restrict__ lstat,
    const float* __restrict__ head_mask, u16* __restrict__ attn_out)
{
  __shared__ __align__(16) u16 vt[64*72];   // transposed V tile: vt[d][s2]
  const int t = threadIdx.x, w = t >> 6, l = t & 63;
  const int bh = blockIdx.y, b = bh >> 4, h = bh & 15;
  const int q0 = blockIdx.x * 64;
  const float hm = head_mask[0];
  const int rowa = q0 + w*16 + (l & 15);
  const float ma  = mstat[bh*1024 + rowa];
  const float rcp = hm / lstat[bh*1024 + rowa];
  float* attn_b = attn + (size_t)bh * 1024 * 1024;

  f32x4 acc[4];
  #pragma unroll
  for (int n=0;n<4;++n) acc[n] = (f32x4){0.f,0.f,0.f,0.f};

  for (int ct = 0; ct < 16; ++ct){
    __syncthreads();
    { // stage V transposed
      int s2 = t >> 2, d0 = (t & 3) * 16;
      const u16* g = qkv + (size_t)(b*1024 + ct*64 + s2) * 3072 + 2048 + h*64 + d0;
      short8 v0 = *(const short8*)g;
      short8 v1 = *(const short8*)(g + 8);
      #pragma unroll
      for (int i=0;i<8;++i) vt[(d0+i)*72 + s2] = (u16)v0[i];
      #pragma unroll
      for (int i=0;i<8;++i) vt[(d0+8+i)*72 + s2] = (u16)v1[i];
    }
    __syncthreads();
    #pragma unroll
    for (int kk=0;kk<2;++kk){
      float* prow = attn_b + (size_t)rowa * 1024 + ct*64 + kk*32 + (l>>4)*8;
      f32x4 f0 = *(const f32x4*)prow;
      f32x4 f1 = *(const f32x4*)(prow + 4);
      f32x4 p0, p1;
      #pragma unroll
      for (int i=0;i<4;++i) p0[i] = expf(f0[i] - ma) * rcp;
      #pragma unroll
      for (int i=0;i<4;++i) p1[i] = expf(f1[i] - ma) * rcp;
      *(f32x4*)prow = p0;
      *(f32x4*)(prow + 4) = p1;
      short8 pa;
      #pragma unroll
      for (int i=0;i<4;++i) pa[i]   = f2bf(p0[i]);
      #pragma unroll
      for (int i=0;i<4;++i) pa[4+i] = f2bf(p1[i]);
      #pragma unroll
      for (int n=0;n<4;++n){
        short8 vf = *(const short8*)&vt[(n*16 + (l&15))*72 + kk*32 + (l>>4)*8];
        acc[n] = __builtin_amdgcn_mfma_f32_16x16x32_bf16(pa, vf, acc[n], 0, 0, 0);
      }
    }
  }
  #pragma unroll
  for (int n=0;n<4;++n){
    int col = h*64 + n*16 + (l & 15);
    #pragma unroll
    for (int j=0;j<4;++j){
      int row = q0 + w*16 + (l>>4)*4 + j;
      attn_out[(size_t)(b*1024 + row) * 1024 + col] = f2bf(acc[n][j]);
    }
  }
}

// ---------------- fused residual + LayerNorm ----------------
// grid: M rows; block 256; each thread 4 elems
__global__ __launch_bounds__(256) void ln_kernel(
    const float* __restrict__ a, const float* __restrict__ r,
    const float* __restrict__ w, const float* __restrict__ b,
    float* __restrict__ outf, u16* __restrict__ outb)
{
  const int row = blockIdx.x, t = threadIdx.x;
  const size_t base = (size_t)row * 1024;
  float v[4];
  float s1 = 0.f, s2 = 0.f;
  #pragma unroll
  for (int i=0;i<4;++i){
    int c = i*256 + t;
    float x = a[base + c] + r[base + c];
    v[i] = x; s1 += x; s2 += x * x;
  }
  #pragma unroll
  for (int o=32;o;o>>=1){ s1 += __shfl_xor(s1, o); s2 += __shfl_xor(s2, o); }
  __shared__ float red[8];
  int wv = t >> 6, l = t & 63;
  if (l == 0){ red[wv] = s1; red[4+wv] = s2; }
  __syncthreads();
  s1 = red[0]+red[1]+red[2]+red[3];
  s2 = red[4]+red[5]+red[6]+red[7];
  float mu  = s1 * (1.f/1024.f);
  float var = s2 * (1.f/1024.f) - mu*mu;
  float rstd = rsqrtf(var + 1e-5f);
  #pragma unroll
  for (int i=0;i<4;++i){
    int c = i*256 + t;
    float y = (v[i]-mu)*rstd*w[c] + b[c];
    if (outf) outf[base + c] = y;
    if (outb) outb[base + c] = f2bf(y);
  }
}

// ---------------- launch ----------------
extern "C" void kernel_launch(void* const* d_in, const int* in_sizes, int n_in,
                              void* d_out, int out_size, void* d_ws, size_t ws_size,
                              hipStream_t stream)
{
  const float* x          = (const float*)d_in[0];
  const float* in_proj_w  = (const float*)d_in[1];
  const float* in_proj_b  = (const float*)d_in[2];
  const float* out_proj_w = (const float*)d_in[3];
  const float* out_proj_b = (const float*)d_in[4];
  const float* ln1_w = (const float*)d_in[5];
  const float* ln1_b = (const float*)d_in[6];
  const float* ln2_w = (const float*)d_in[7];
  const float* ln2_b = (const float*)d_in[8];
  const float* ffn_w1 = (const float*)d_in[9];
  const float* ffn_b1 = (const float*)d_in[10];
  const float* ffn_w2 = (const float*)d_in[11];
  const float* ffn_b2 = (const float*)d_in[12];
  const float* head_mask = (const float*)d_in[13];

  const int B = 8, S = 1024, D = 1024, DFF = 4096;
  const int M = B * S;                         // 8192

  char* ws = (char*)d_ws;
  u16*   qkv_bf = (u16*)ws;                              // 50331648 B
  char*  r1 = ws + 50331648;                             // 23068672 B region
  u16*   x_bf    = (u16*)r1;                             // 16777216
  u16*   wqkv_bf = (u16*)(r1 + 16777216);                // 6291456
  u16*   w1_bf   = (u16*)r1;                             // 8388608 (reuse after QKV gemm)
  u16*   w2_bf   = (u16*)(r1 + 8388608);                 // 8388608
  u16*   wout_bf = (u16*)(r1 + 16777216);                // 2097152
  char*  p2 = ws + 50331648 + 23068672;
  float* mstat = (float*)p2;                             // 524288
  float* lstat = (float*)(p2 + 524288);                  // 524288
  u16*   attn_out_bf = (u16*)(p2 + 1048576);             // 16777216 (later x1_bf)
  u16*   x1_bf = attn_out_bf;
  float* proj = (float*)(p2 + 1048576 + 16777216);       // 33554432 (later ff)
  float* ff = proj;
  float* x1 = (float*)((char*)proj + 33554432);          // 33554432
  u16*   h_bf = (u16*)((char*)x1 + 33554432);            // 67108864

  float* out  = (float*)d_out;        // 8388608 floats
  float* attn = out + 8388608;        // 134217728 floats (scratch: raw scores, then final attn)

  cast_bf16<<<(M*D/8 + 255)/256, 256, 0, stream>>>(x, x_bf, M*D/8);
  cast_bf16<<<(3*D*D/8 + 255)/256, 256, 0, stream>>>(in_proj_w, wqkv_bf, 3*D*D/8);

  gemm_bt<u16,false><<<dim3(3*D/128, M/128), 256, 0, stream>>>(x_bf, wqkv_bf, in_proj_b, qkv_bf, M, 3*D, D);

  cast_bf16<<<(D*D/8 + 255)/256, 256, 0, stream>>>(out_proj_w, wout_bf, D*D/8);
  cast_bf16<<<(DFF*D/8 + 255)/256, 256, 0, stream>>>(ffn_w1, w1_bf, DFF*D/8);
  cast_bf16<<<(D*DFF/8 + 255)/256, 256, 0, stream>>>(ffn_w2, w2_bf, D*DFF/8);

  attn_qk<<<dim3(16, 128), 256, 0, stream>>>(qkv_bf, attn, mstat, lstat);
  attn_pv<<<dim3(16, 128), 256, 0, stream>>>(qkv_bf, attn, mstat, lstat, head_mask, attn_out_bf);

  gemm_bt<float,false><<<dim3(D/128, M/128), 256, 0, stream>>>(attn_out_bf, wout_bf, out_proj_b, proj, M, D, D);
  ln_kernel<<<M, 256, 0, stream>>>(proj, x, ln1_w, ln1_b, x1, x1_bf);
  gemm_bt<u16,true><<<dim3(DFF/128, M/128), 256, 0, stream>>>(x1_bf, w1_bf, ffn_b1, h_bf, M, DFF, D);
  gemm_bt<float,false><<<dim3(D/128, M/128), 256, 0, stream>>>(h_bf, w2_bf, ffn_b2, ff, M, D, DFF);
  ln_kernel<<<M, 256, 0, stream>>>(ff, x1, ln2_w, ln2_b, out, (u16*)nullptr);
}

// Round 2
// 653.037 us; speedup vs baseline: 1.3147x; 1.3147x over previous
//
#include <hip/hip_runtime.h>

typedef unsigned short u16;
typedef __attribute__((ext_vector_type(8))) short short8;
typedef __attribute__((ext_vector_type(4))) float f32x4;

__device__ __forceinline__ u16 f2bf(float f){
  unsigned u = __builtin_bit_cast(unsigned, f);
  u += 0x7fffu + ((u >> 16) & 1u);
  return (u16)(u >> 16);
}

#define GLD16(gp, lp) __builtin_amdgcn_global_load_lds(                         \
    (const __attribute__((address_space(1))) void*)(gp),                        \
    (__attribute__((address_space(3))) void*)(lp), 16, 0, 0)

// ---------------- cast fp32 -> bf16, 8 elems/thread ----------------
__global__ __launch_bounds__(256) void cast_bf16(const float* __restrict__ in,
                                                 u16* __restrict__ out, int n8){
  int i = blockIdx.x * blockDim.x + threadIdx.x;
  if (i >= n8) return;
  const f32x4* p = (const f32x4*)in + (size_t)i * 2;
  f32x4 a = p[0], b = p[1];
  short8 o;
  o[0]=f2bf(a[0]); o[1]=f2bf(a[1]); o[2]=f2bf(a[2]); o[3]=f2bf(a[3]);
  o[4]=f2bf(b[0]); o[5]=f2bf(b[1]); o[6]=f2bf(b[2]); o[7]=f2bf(b[3]);
  *(short8*)(out + (size_t)i * 8) = o;
}

// ---------------- GEMM  C[M,N] = A[M,K] @ B[N,K]^T + bias ----------------
__device__ __forceinline__ void store_val(float* p, float v){ *p = v; }
__device__ __forceinline__ void store_val(u16* p, float v){ *p = f2bf(v); }

template<typename OutT, bool RELU>
__global__ __launch_bounds__(256) void gemm_bt(
    const u16* __restrict__ A, const u16* __restrict__ B,
    const float* __restrict__ bias, OutT* __restrict__ C,
    int M, int N, int K)
{
  __shared__ __align__(16) u16 a_lds[2][128*32];
  __shared__ __align__(16) u16 b_lds[2][128*32];
  const int t = threadIdx.x, w = t >> 6, l = t & 63;
  const int m0 = blockIdx.y * 128, n0 = blockIdx.x * 128;
  const int wr = (w >> 1) * 64, wc = (w & 1) * 64;

  auto stage = [&](int buf, int kt){
    const int k0 = kt * 32;
    #pragma unroll
    for (int i = 0; i < 2; ++i){
      int s = w * 2 + i;
      const u16* ga = A + (size_t)(m0 + s*16 + (l>>2)) * K + k0 + (l&3)*8;
      GLD16(ga, &a_lds[buf][s*512]);
      const u16* gb = B + (size_t)(n0 + s*16 + (l>>2)) * K + k0 + (l&3)*8;
      GLD16(gb, &b_lds[buf][s*512]);
    }
  };

  f32x4 acc[4][4];
  #pragma unroll
  for (int m=0;m<4;++m)
    #pragma unroll
    for (int n=0;n<4;++n) acc[m][n] = (f32x4){0.f,0.f,0.f,0.f};

  stage(0, 0);
  __syncthreads();
  const int nk = K / 32;
  int cur = 0;
  for (int kt = 0; kt < nk; ++kt){
    if (kt + 1 < nk) stage(cur ^ 1, kt + 1);
    short8 af[4], bfr[4];
    #pragma unroll
    for (int m=0;m<4;++m)
      af[m] = *(const short8*)&a_lds[cur][(wr + m*16 + (l&15))*32 + (l>>4)*8];
    #pragma unroll
    for (int n=0;n<4;++n)
      bfr[n] = *(const short8*)&b_lds[cur][(wc + n*16 + (l&15))*32 + (l>>4)*8];
    #pragma unroll
    for (int m=0;m<4;++m)
      #pragma unroll
      for (int n=0;n<4;++n)
        acc[m][n] = __builtin_amdgcn_mfma_f32_16x16x32_bf16(af[m], bfr[n], acc[m][n], 0, 0, 0);
    __syncthreads();
    cur ^= 1;
  }

  #pragma unroll
  for (int n=0;n<4;++n){
    int c = n0 + wc + n*16 + (l & 15);
    float bv = bias ? bias[c] : 0.f;
    #pragma unroll
    for (int m=0;m<4;++m){
      int rbase = m0 + wr + m*16 + (l >> 4) * 4;
      #pragma unroll
      for (int j=0;j<4;++j){
        float v = acc[m][n][j] + bv;
        if (RELU) v = fmaxf(v, 0.f);
        store_val(&C[(size_t)(rbase + j) * N + c], v);
      }
    }
  }
}

// ---------------- fused attention: online stats + recompute + PV ----------------
// grid: (S/64, B*H); block 256 (4 waves, each 16 q-rows)
// Pass 1: QK^T tiles, track per-row m,l (no stores).
// Pass 2: recompute QK^T (bitwise-identical), write normalized attn (fp32),
//         repack P->bf16 via LDS, PV MFMA with transposed V in LDS.
// K/Q LDS tiles use a source-pre-swizzle (col chunk rotated by 16*(row&3)) so
// ds_read_b128 column-slices are bank-conflict free while global_load_lds
// keeps a linear destination.
__global__ __launch_bounds__(256) void attn_fused(
    const u16* __restrict__ qkv, float* __restrict__ attn,
    const float* __restrict__ head_mask, u16* __restrict__ attn_out)
{
  __shared__ __align__(16) u16 qs[64*64];       // 8 KB
  __shared__ __align__(16) u16 ks[2][64*64];    // 16 KB
  __shared__ __align__(16) u16 vt[64*72];       // 9 KB  vt[d][s] (stride 72)
  __shared__ __align__(16) u16 pl[64*72];       // 9 KB  pl[q][s] (stride 72)
  const int t = threadIdx.x, w = t >> 6, l = t & 63;
  const int bh = blockIdx.y, b = bh >> 4, h = bh & 15;
  const int q0 = blockIdx.x * 64;
  const size_t qbase = (size_t)b * 1024 * 3072;
  const float hm = head_mask[0];

  // ---- staging helpers (pre-swizzled source, linear LDS dest) ----
  auto stageQ = [&](){
    #pragma unroll
    for (int i=0;i<2;++i){
      int s = w*2 + i;
      int row = s*8 + (l>>3);
      int gcol = (8*(l&7) - 16*(row&3)) & 63;
      const u16* g = qkv + qbase + (size_t)(q0 + row) * 3072 + h*64 + gcol;
      GLD16(g, &qs[s*512]);
    }
  };
  auto stageK = [&](int buf, int ct){
    #pragma unroll
    for (int i=0;i<2;++i){
      int s = w*2 + i;
      int row = s*8 + (l>>3);
      int gcol = (8*(l&7) - 16*(row&3)) & 63;
      const u16* g = qkv + qbase + (size_t)(ct*64 + row) * 3072 + 1024 + h*64 + gcol;
      GLD16(g, &ks[buf][s*512]);
    }
  };

  stageQ();
  stageK(0, 0);
  __syncthreads();

  // Q fragments (read once, swizzled cols)
  const int rq = w*16 + (l&15);
  const int qrot = 16*(rq&3);
  short8 a0 = *(const short8*)&qs[rq*64 + (((l>>4)*8      + qrot) & 63)];
  short8 a1 = *(const short8*)&qs[rq*64 + (((l>>4)*8 + 32 + qrot) & 63)];

  auto qkmma = [&](int buf, f32x4* acc){
    #pragma unroll
    for (int n=0;n<4;++n){
      int r = n*16 + (l&15);
      int rot = 16*(r&3);
      short8 b0 = *(const short8*)&ks[buf][r*64 + (((l>>4)*8      + rot) & 63)];
      acc[n] = __builtin_amdgcn_mfma_f32_16x16x32_bf16(a0, b0, acc[n], 0, 0, 0);
    }
    #pragma unroll
    for (int n=0;n<4;++n){
      int r = n*16 + (l&15);
      int rot = 16*(r&3);
      short8 b1 = *(const short8*)&ks[buf][r*64 + (((l>>4)*8 + 32 + rot) & 63)];
      acc[n] = __builtin_amdgcn_mfma_f32_16x16x32_bf16(a1, b1, acc[n], 0, 0, 0);
    }
  };

  // ---- pass 1: online m,l ----
  float m_run[4] = {-1e30f,-1e30f,-1e30f,-1e30f};
  float l_run[4] = {0.f,0.f,0.f,0.f};
  int cur = 0;
  for (int ct = 0; ct < 16; ++ct){
    if (ct < 15) stageK(cur ^ 1, ct + 1);
    f32x4 acc[4];
    #pragma unroll
    for (int n=0;n<4;++n) acc[n] = (f32x4){0.f,0.f,0.f,0.f};
    qkmma(cur, acc);
    #pragma unroll
    for (int j=0;j<4;++j){
      float s0 = acc[0][j]*0.125f, s1 = acc[1][j]*0.125f;
      float s2 = acc[2][j]*0.125f, s3 = acc[3][j]*0.125f;
      float mx = fmaxf(fmaxf(s0,s1), fmaxf(s2,s3));
      #pragma unroll
      for (int o=1;o<16;o<<=1) mx = fmaxf(mx, __shfl_xor(mx, o));
      float mn = fmaxf(m_run[j], mx);
      float es = __expf(s0-mn) + __expf(s1-mn) + __expf(s2-mn) + __expf(s3-mn);
      #pragma unroll
      for (int o=1;o<16;o<<=1) es += __shfl_xor(es, o);
      l_run[j] = l_run[j] * __expf(m_run[j] - mn) + es;
      m_run[j] = mn;
    }
    __syncthreads();
    cur ^= 1;
  }

  float rcp[4];
  #pragma unroll
  for (int j=0;j<4;++j) rcp[j] = hm / l_run[j];

  // ---- pass 2: recompute, normalize, write attn, PV ----
  float* attn_b = attn + (size_t)bh * 1024 * 1024;
  const int kv = t & 31, u = t >> 5;     // V staging partition: s-pair, d-group
  f32x4 accO[4];
  #pragma unroll
  for (int n=0;n<4;++n) accO[n] = (f32x4){0.f,0.f,0.f,0.f};

  stageK(0, 0);                 // cur == 0 after 16 flips
  for (int ct = 0; ct < 16; ++ct){
    // V tile -> registers (HBM/L3 latency hides under the barrier+QK phase)
    const u16* gv = qkv + qbase + (size_t)(1024*2 /*offset within row handled below*/, 0), *dummy = nullptr; (void)dummy;
    const u16* g0 = qkv + qbase + (size_t)(ct*64 + 2*kv) * 3072 + 2048 + h*64 + u*8;
    short8 v0 = *(const short8*)g0;
    short8 v1 = *(const short8*)(g0 + 3072);

    __syncthreads();                       // B1: ks[cur] staged; prior PV reads done
    if (ct < 15) stageK(cur ^ 1, ct + 1);  // overlaps QK + epilogue, drains at B2

    f32x4 acc2[4];
    #pragma unroll
    for (int n=0;n<4;++n) acc2[n] = (f32x4){0.f,0.f,0.f,0.f};
    qkmma(cur, acc2);

    #pragma unroll
    for (int j=0;j<4;++j){
      int rloc = w*16 + (l>>4)*4 + j;
      float p0 = __expf(acc2[0][j]*0.125f - m_run[j]) * rcp[j];
      float p1 = __expf(acc2[1][j]*0.125f - m_run[j]) * rcp[j];
      float p2 = __expf(acc2[2][j]*0.125f - m_run[j]) * rcp[j];
      float p3 = __expf(acc2[3][j]*0.125f - m_run[j]) * rcp[j];
      float* ap = attn_b + (size_t)(q0 + rloc) * 1024 + ct*64 + (l&15);
      ap[0] = p0; ap[16] = p1; ap[32] = p2; ap[48] = p3;
      u16* pp = &pl[rloc*72 + (l&15)];
      pp[0] = f2bf(p0); pp[16] = f2bf(p1); pp[32] = f2bf(p2); pp[48] = f2bf(p3);
    }
    // transposed V tile: paired b32 writes (bank-conflict free)
    #pragma unroll
    for (int i=0;i<8;++i){
      unsigned wrd = (unsigned)(u16)v0[i] | ((unsigned)(u16)v1[i] << 16);
      *(unsigned*)&vt[(u*8 + i)*72 + 2*kv] = wrd;
    }
    __syncthreads();                       // B2: pl, vt visible
    #pragma unroll
    for (int kk=0;kk<2;++kk){
      short8 pa = *(const short8*)&pl[(w*16 + (l&15))*72 + kk*32 + (l>>4)*8];
      #pragma unroll
      for (int n=0;n<4;++n){
        short8 vf = *(const short8*)&vt[(n*16 + (l&15))*72 + kk*32 + (l>>4)*8];
        accO[n] = __builtin_amdgcn_mfma_f32_16x16x32_bf16(pa, vf, accO[n], 0, 0, 0);
      }
    }
    cur ^= 1;
  }

  #pragma unroll
  for (int n=0;n<4;++n){
    int col = h*64 + n*16 + (l & 15);
    #pragma unroll
    for (int j=0;j<4;++j){
      int row = q0 + w*16 + (l>>4)*4 + j;
      attn_out[(size_t)(b*1024 + row) * 1024 + col] = f2bf(accO[n][j]);
    }
  }
}

// ---------------- fused residual + LayerNorm ----------------
__global__ __launch_bounds__(256) void ln_kernel(
    const float* __restrict__ a, const float* __restrict__ r,
    const float* __restrict__ w, const float* __restrict__ b,
    float* __restrict__ outf, u16* __restrict__ outb)
{
  const int row = blockIdx.x, t = threadIdx.x;
  const size_t base = (size_t)row * 1024;
  float v[4];
  float s1 = 0.f, s2 = 0.f;
  #pragma unroll
  for (int i=0;i<4;++i){
    int c = i*256 + t;
    float x = a[base + c] + r[base + c];
    v[i] = x; s1 += x; s2 += x * x;
  }
  #pragma unroll
  for (int o=32;o;o>>=1){ s1 += __shfl_xor(s1, o); s2 += __shfl_xor(s2, o); }
  __shared__ float red[8];
  int wv = t >> 6, l = t & 63;
  if (l == 0){ red[wv] = s1; red[4+wv] = s2; }
  __syncthreads();
  s1 = red[0]+red[1]+red[2]+red[3];
  s2 = red[4]+red[5]+red[6]+red[7];
  float mu  = s1 * (1.f/1024.f);
  float var = s2 * (1.f/1024.f) - mu*mu;
  float rstd = rsqrtf(var + 1e-5f);
  #pragma unroll
  for (int i=0;i<4;++i){
    int c = i*256 + t;
    float y = (v[i]-mu)*rstd*w[c] + b[c];
    if (outf) outf[base + c] = y;
    if (outb) outb[base + c] = f2bf(y);
  }
}

// ---------------- launch ----------------
extern "C" void kernel_launch(void* const* d_in, const int* in_sizes, int n_in,
                              void* d_out, int out_size, void* d_ws, size_t ws_size,
                              hipStream_t stream)
{
  const float* x          = (const float*)d_in[0];
  const float* in_proj_w  = (const float*)d_in[1];
  const float* in_proj_b  = (const float*)d_in[2];
  const float* out_proj_w = (const float*)d_in[3];
  const float* out_proj_b = (const float*)d_in[4];
  const float* ln1_w = (const float*)d_in[5];
  const float* ln1_b = (const float*)d_in[6];
  const float* ln2_w = (const float*)d_in[7];
  const float* ln2_b = (const float*)d_in[8];
  const float* ffn_w1 = (const float*)d_in[9];
  const float* ffn_b1 = (const float*)d_in[10];
  const float* ffn_w2 = (const float*)d_in[11];
  const float* ffn_b2 = (const float*)d_in[12];
  const float* head_mask = (const float*)d_in[13];

  const int B = 8, S = 1024, D = 1024, DFF = 4096;
  const int M = B * S;                         // 8192

  char* ws = (char*)d_ws;
  u16*   qkv_bf = (u16*)ws;                              // 50331648 B
  char*  r1 = ws + 50331648;
  u16*   x_bf    = (u16*)r1;                             // 16777216
  u16*   wqkv_bf = (u16*)(r1 + 16777216);                // 6291456
  u16*   w1_bf   = (u16*)r1;                             // 8388608 (reuse after QKV gemm)
  u16*   w2_bf   = (u16*)(r1 + 8388608);                 // 8388608
  u16*   wout_bf = (u16*)(r1 + 16777216);                // 2097152
  char*  p2 = ws + 50331648 + 23068672;
  u16*   attn_out_bf = (u16*)(p2 + 1048576);             // 16777216 (later x1_bf)
  u16*   x1_bf = attn_out_bf;
  float* proj = (float*)(p2 + 1048576 + 16777216);       // 33554432 (later ff)
  float* ff = proj;
  float* x1 = (float*)((char*)proj + 33554432);          // 33554432
  u16*   h_bf = (u16*)((char*)x1 + 33554432);            // 67108864

  float* out  = (float*)d_out;        // 8388608 floats
  float* attn = out + 8388608;        // 134217728 floats (final attn, written once)

  cast_bf16<<<(M*D/8 + 255)/256, 256, 0, stream>>>(x, x_bf, M*D/8);
  cast_bf16<<<(3*D*D/8 + 255)/256, 256, 0, stream>>>(in_proj_w, wqkv_bf, 3*D*D/8);

  gemm_bt<u16,false><<<dim3(3*D/128, M/128), 256, 0, stream>>>(x_bf, wqkv_bf, in_proj_b, qkv_bf, M, 3*D, D);

  cast_bf16<<<(D*D/8 + 255)/256, 256, 0, stream>>>(out_proj_w, wout_bf, D*D/8);
  cast_bf16<<<(DFF*D/8 + 255)/256, 256, 0, stream>>>(ffn_w1, w1_bf, DFF*D/8);
  cast_bf16<<<(D*DFF/8 + 255)/256, 256, 0, stream>>>(ffn_w2, w2_bf, D*DFF/8);

  attn_fused<<<dim3(16, 128), 256, 0, stream>>>(qkv_bf, attn, head_mask, attn_out_bf);

  gemm_bt<float,false><<<dim3(D/128, M/128), 256, 0, stream>>>(attn_out_bf, wout_bf, out_proj_b, proj, M, D, D);
  ln_kernel<<<M, 256, 0, stream>>>(proj, x, ln1_w, ln1_b, x1, x1_bf);
  gemm_bt<u16,true><<<dim3(DFF/128, M/128), 256, 0, stream>>>(x1_bf, w1_bf, ffn_b1, h_bf, M, DFF, D);
  gemm_bt<float,false><<<dim3(D/128, M/128), 256, 0, stream>>>(h_bf, w2_bf, ffn_b2, ff, M, D, DFF);
  ln_kernel<<<M, 256, 0, stream>>>(ff, x1, ln2_w, ln2_b, out, (u16*)nullptr);
}